// Round 8
// baseline (501.617 us; speedup 1.0000x reference)
//
#include <hip/hip_runtime.h>
#include <hip/hip_fp16.h>

#define N_NODES 200000
#define N_EDGES 1000000
#define N_GRAPHS 4096
#define F_IN 11
#define H 64
#define XP 16   // padded row stride for 11-wide buffers

// ---------------- degree histogram over dst ----------------

__global__ void deg_kernel(const int* __restrict__ dst, int* __restrict__ deg) {
    int i = blockIdx.x * blockDim.x + threadIdx.x;
    if (i < N_EDGES) atomicAdd(&deg[dst[i]], 1);
}

__global__ void batch_cnt_kernel(const int* __restrict__ batch, int* __restrict__ cnts) {
    int i = blockIdx.x * blockDim.x + threadIdx.x;
    if (i < N_NODES) atomicAdd(&cnts[batch[i]], 1);
}

// ---------------- CSR build: block scan + top scan + add + place ----------------

__global__ void scan_block_kernel(const int* __restrict__ deg, int* __restrict__ ex,
                                  int* __restrict__ bsum, float* __restrict__ dis) {
    __shared__ int sh[256];
    int i = blockIdx.x * 256 + threadIdx.x;
    int v = (i < N_NODES) ? deg[i] : 0;
    if (i < N_NODES) dis[i] = rsqrtf((float)(v + 1));   // +1 self loop
    sh[threadIdx.x] = v;
    __syncthreads();
    for (int o = 1; o < 256; o <<= 1) {
        int t = (threadIdx.x >= o) ? sh[threadIdx.x - o] : 0;
        __syncthreads();
        sh[threadIdx.x] += t;
        __syncthreads();
    }
    if (i < N_NODES) ex[i] = sh[threadIdx.x] - v;       // exclusive
    if (threadIdx.x == 255) bsum[blockIdx.x] = sh[255];
}

__global__ void scan_top_kernel(int* __restrict__ bsum, int nb) {
    __shared__ int sh[1024];
    int v = ((int)threadIdx.x < nb) ? bsum[threadIdx.x] : 0;
    sh[threadIdx.x] = v;
    __syncthreads();
    for (int o = 1; o < 1024; o <<= 1) {
        int t = ((int)threadIdx.x >= o) ? sh[threadIdx.x - o] : 0;
        __syncthreads();
        sh[threadIdx.x] += t;
        __syncthreads();
    }
    if ((int)threadIdx.x < nb) bsum[threadIdx.x] = sh[threadIdx.x] - v;
}

__global__ void scan_add_kernel(const int* __restrict__ ex, const int* __restrict__ boff,
                                int* __restrict__ row_start, int* __restrict__ cursor) {
    int i = blockIdx.x * 256 + threadIdx.x;
    if (i >= N_NODES) return;
    int r = ex[i] + boff[i >> 8];
    row_start[i] = r;
    cursor[i] = r;
    if (i == 0) row_start[N_NODES] = N_EDGES;
}

__global__ void place_kernel(const int* __restrict__ src, const int* __restrict__ dst,
                             int* __restrict__ cursor, int* __restrict__ csr) {
    int e = blockIdx.x * blockDim.x + threadIdx.x;
    if (e < N_EDGES) {
        int p = atomicAdd(&cursor[dst[e]], 1);
        csr[p] = src[e];
    }
}

// ---------------- xs[row*16+c] = x*dis (c<11), 0 pad ----------------

__global__ void xscale_kernel(const float* __restrict__ x, const float* __restrict__ dis,
                              float* __restrict__ xs) {
    int i = blockIdx.x * blockDim.x + threadIdx.x;
    if (i < N_NODES * XP) {
        int row = i >> 4;
        int c = i & 15;
        xs[i] = (c < F_IN) ? x[(size_t)row * F_IN + c] * dis[row] : 0.f;
    }
}

// ---------------- layer-1 gather on padded 16-wide xs ----------------
// 4 nodes per wave: u = lane>>4, c = lane&15. P[n*16+c] = dis[n]*sum (pad cols sum zeros).

__global__ void gather1_kernel(const int* __restrict__ row_start, const int* __restrict__ csr,
                               const float* __restrict__ xs, const float* __restrict__ dis,
                               float* __restrict__ P) {
    int lane = threadIdx.x & 63;
    int c = lane & 15;
    int u = lane >> 4;
    int wave = (blockIdx.x * blockDim.x + threadIdx.x) >> 6;
    int nw = (gridDim.x * blockDim.x) >> 6;
    for (int n4 = wave * 4; n4 < N_NODES; n4 += nw * 4) {
        int n = n4 + u;
        int e0 = row_start[n], e1 = row_start[n + 1];
        float acc = xs[(size_t)n * XP + c];            // self loop
        int e = e0;
        for (; e + 4 <= e1; e += 4) {
            int s0 = csr[e], s1 = csr[e + 1], s2 = csr[e + 2], s3 = csr[e + 3];
            float v0 = xs[(size_t)s0 * XP + c];
            float v1 = xs[(size_t)s1 * XP + c];
            float v2 = xs[(size_t)s2 * XP + c];
            float v3 = xs[(size_t)s3 * XP + c];
            acc += (v0 + v1) + (v2 + v3);
        }
        for (; e < e1; ++e) acc += xs[(size_t)csr[e] * XP + c];
        P[(size_t)n * XP + c] = acc * dis[n];
    }
}

// ---------------- register-tiled dense transform ----------------
// 64 rows/block, 256 threads, 4x4 per thread.
// HALF_OUT: Y = half((X@W)*dis[row]).  else: Y = relu(X@W + bias) f32.

template <int K, bool HALF_OUT>
__global__ void gemm_tile_kernel(const float* __restrict__ X, const float* __restrict__ W,
                                 const float* __restrict__ dis, const float* __restrict__ bias,
                                 void* __restrict__ Y) {
    constexpr int KS = (K == F_IN) ? XP : K;
    __shared__ float Xt[KS][68];
    __shared__ float Ws[K][64];
    int tid = threadIdx.x;
    int rowbase = blockIdx.x * 64;

    for (int i = tid; i < K * 64; i += 256) Ws[i >> 6][i & 63] = W[i];

    if (K == 64) {
        for (int t = tid; t < 1024; t += 256) {
            int r = t >> 4;
            int kc = (t & 15) * 4;
            float4 v = *(const float4*)(X + (size_t)(rowbase + r) * 64 + kc);
            Xt[kc + 0][r] = v.x;
            Xt[kc + 1][r] = v.y;
            Xt[kc + 2][r] = v.z;
            Xt[kc + 3][r] = v.w;
        }
    } else {
        // padded rows of 16 floats: 64*16 = 1024 floats = 256 float4, 1/thread
        int r = tid >> 2;
        int c4 = (tid & 3) * 4;
        float4 v = *(const float4*)(X + (size_t)(rowbase + r) * XP + c4);
        Xt[c4 + 0][r] = v.x;
        Xt[c4 + 1][r] = v.y;
        Xt[c4 + 2][r] = v.z;
        Xt[c4 + 3][r] = v.w;
    }
    __syncthreads();

    int tc = (tid & 15) * 4;
    int tr = (tid >> 4) * 4;
    float a00 = 0, a01 = 0, a02 = 0, a03 = 0;
    float a10 = 0, a11 = 0, a12 = 0, a13 = 0;
    float a20 = 0, a21 = 0, a22 = 0, a23 = 0;
    float a30 = 0, a31 = 0, a32 = 0, a33 = 0;
#pragma unroll
    for (int k = 0; k < K; ++k) {
        float4 xv = *(const float4*)&Xt[k][tr];
        float4 wv = *(const float4*)&Ws[k][tc];
        a00 += xv.x * wv.x; a01 += xv.x * wv.y; a02 += xv.x * wv.z; a03 += xv.x * wv.w;
        a10 += xv.y * wv.x; a11 += xv.y * wv.y; a12 += xv.y * wv.z; a13 += xv.y * wv.w;
        a20 += xv.z * wv.x; a21 += xv.z * wv.y; a22 += xv.z * wv.z; a23 += xv.z * wv.w;
        a30 += xv.w * wv.x; a31 += xv.w * wv.y; a32 += xv.w * wv.z; a33 += xv.w * wv.w;
    }
    float acc[4][4] = {{a00, a01, a02, a03}, {a10, a11, a12, a13},
                       {a20, a21, a22, a23}, {a30, a31, a32, a33}};
    float4 bv = {0, 0, 0, 0};
    if (!HALF_OUT) bv = *(const float4*)(bias + tc);
#pragma unroll
    for (int i = 0; i < 4; ++i) {
        int row = rowbase + tr + i;
        if (HALF_OUT) {
            float d = dis[row];
            union { uint2 u; __half2 h[2]; } pk;
            pk.h[0] = __floats2half2_rn(acc[i][0] * d, acc[i][1] * d);
            pk.h[1] = __floats2half2_rn(acc[i][2] * d, acc[i][3] * d);
            *(uint2*)((__half*)Y + (size_t)row * 64 + tc) = pk.u;
        } else {
            float4 o;
            o.x = fmaxf(acc[i][0] + bv.x, 0.f);
            o.y = fmaxf(acc[i][1] + bv.y, 0.f);
            o.z = fmaxf(acc[i][2] + bv.z, 0.f);
            o.w = fmaxf(acc[i][3] + bv.w, 0.f);
            *(float4*)((float*)Y + (size_t)row * 64 + tc) = o;
        }
    }
}

// ---------------- CSR gather on fp16 rows, slot-parallel (layer 2) ----------------
// lane = g*16 + q : g = edge-slot group (0..3), q = 4-half quad (0..15).
// A[n] = relu( dis[n] * sum_slots Bsh[src] + bias )  f32 out.

__global__ void gather_kernel(const int* __restrict__ row_start, const int* __restrict__ csr,
                              const __half* __restrict__ Bsh, const float* __restrict__ dis,
                              const float* __restrict__ bias, float* __restrict__ A) {
    int lane = threadIdx.x & 63;
    int q = lane & 15;
    int g = lane >> 4;
    int wave = (blockIdx.x * blockDim.x + threadIdx.x) >> 6;
    int nw = (gridDim.x * blockDim.x) >> 6;
    float4 bi = ((const float4*)bias)[q];
    for (int n = wave; n < N_NODES; n += nw) {
        int e0 = row_start[n], e1 = row_start[n + 1];
        int nslots = e1 - e0 + 1;
        float4 acc = {0.f, 0.f, 0.f, 0.f};
        for (int base = 0; base < nslots; base += 4) {
            int slot = base + g;
            if (slot < nslots) {
                int s = (slot == 0) ? n : csr[e0 + slot - 1];
                union { uint2 u; __half2 h[2]; } r;
                r.u = *(const uint2*)(Bsh + (size_t)s * 64 + q * 4);
                float2 f0 = __half22float2(r.h[0]);
                float2 f1 = __half22float2(r.h[1]);
                acc.x += f0.x; acc.y += f0.y; acc.z += f1.x; acc.w += f1.y;
            }
        }
#pragma unroll
        for (int m = 16; m <= 32; m <<= 1) {
            acc.x += __shfl_xor(acc.x, m, 64);
            acc.y += __shfl_xor(acc.y, m, 64);
            acc.z += __shfl_xor(acc.z, m, 64);
            acc.w += __shfl_xor(acc.w, m, 64);
        }
        if (g == 0) {
            float d = dis[n];
            float4 o;
            o.x = fmaxf(acc.x * d + bi.x, 0.f);
            o.y = fmaxf(acc.y * d + bi.y, 0.f);
            o.z = fmaxf(acc.z * d + bi.z, 0.f);
            o.w = fmaxf(acc.w * d + bi.w, 0.f);
            *(float4*)(A + (size_t)n * 64 + q * 4) = o;
        }
    }
}

// ---------------- layer-3 gather (fp16) + in-register dot(lin_w) + scalar pool ----------

__global__ void gather_dot_pool_kernel(const int* __restrict__ row_start,
                                       const int* __restrict__ csr,
                                       const __half* __restrict__ Bsh,
                                       const float* __restrict__ dis,
                                       const float* __restrict__ lw,
                                       const int* __restrict__ batch,
                                       float* __restrict__ gsum) {
    int lane = threadIdx.x & 63;
    int q = lane & 15;
    int g = lane >> 4;
    int wave = (blockIdx.x * blockDim.x + threadIdx.x) >> 6;
    int nw = (gridDim.x * blockDim.x) >> 6;
    float4 lw4 = ((const float4*)lw)[q];
    for (int n = wave; n < N_NODES; n += nw) {
        int e0 = row_start[n], e1 = row_start[n + 1];
        int nslots = e1 - e0 + 1;
        float4 acc = {0.f, 0.f, 0.f, 0.f};
        for (int base = 0; base < nslots; base += 4) {
            int slot = base + g;
            if (slot < nslots) {
                int s = (slot == 0) ? n : csr[e0 + slot - 1];
                union { uint2 u; __half2 h[2]; } r;
                r.u = *(const uint2*)(Bsh + (size_t)s * 64 + q * 4);
                float2 f0 = __half22float2(r.h[0]);
                float2 f1 = __half22float2(r.h[1]);
                acc.x += f0.x; acc.y += f0.y; acc.z += f1.x; acc.w += f1.y;
            }
        }
        float p = acc.x * lw4.x + acc.y * lw4.y + acc.z * lw4.z + acc.w * lw4.w;
#pragma unroll
        for (int m = 1; m <= 32; m <<= 1) p += __shfl_xor(p, m, 64);
        if (lane == 0) atomicAdd(&gsum[batch[n]], p * dis[n]);
    }
}

// ---------------- head: out[g] = gsum/cnt + dot(b3,lw) + lb ----------------

__global__ void head2_kernel(const float* __restrict__ gsum, const int* __restrict__ cnts,
                             const float* __restrict__ b3, const float* __restrict__ lw,
                             const float* __restrict__ lb, float* __restrict__ out) {
    int g = blockIdx.x * blockDim.x + threadIdx.x;
    if (g >= N_GRAPHS) return;
    float cb = 0.f;
#pragma unroll
    for (int k = 0; k < H; ++k) cb += b3[k] * lw[k];
    int c = cnts[g];
    out[g] = (c > 0) ? (gsum[g] / (float)c + cb + lb[0]) : lb[0];
}

extern "C" void kernel_launch(void* const* d_in, const int* in_sizes, int n_in,
                              void* d_out, int out_size, void* d_ws, size_t ws_size,
                              hipStream_t stream) {
    const float* x     = (const float*)d_in[0];
    const int*   ei    = (const int*)d_in[1];
    const int*   batch = (const int*)d_in[2];
    const float* W1    = (const float*)d_in[3];
    const float* b1    = (const float*)d_in[4];
    const float* W2    = (const float*)d_in[5];
    const float* b2    = (const float*)d_in[6];
    const float* W3    = (const float*)d_in[7];
    const float* b3    = (const float*)d_in[8];
    const float* lw    = (const float*)d_in[9];
    const float* lb    = (const float*)d_in[10];
    float* out = (float*)d_out;

    const int* src = ei;
    const int* dst = ei + N_EDGES;

    const size_t NH = (size_t)N_NODES * H;
    char* ws = (char*)d_ws;
    float*  A         = (float*)ws;                                    // 51.2 MB (h1/h2 f32)
    char*   Bregion   = ws + NH * 4;                                   // 51.2 MB
    __half* Bsh       = (__half*)Bregion;                              // 25.6 MB fp16 staging
    float*  dis       = (float*)(ws + 2 * NH * 4);                     // 0.8 MB
    int*    row_start = (int*)(ws + 2 * NH * 4 + (size_t)N_NODES * 4); // 0.8 MB (+1)
    int*    csr       = (int*)((char*)row_start + ((size_t)N_NODES + 1) * 4); // 4 MB
    float*  gsum      = (float*)((char*)csr + (size_t)N_EDGES * 4);    // 16 KB
    int*    cnts      = (int*)((char*)gsum + (size_t)N_GRAPHS * 4);    // 16 KB
    // layer-1 transients inside B region (consumed before Bsh is written by gemm2)
    float* xs = (float*)Bregion;                        // 12.8 MB (16-padded)
    float* P  = (float*)(Bregion + (16u << 20));        // 12.8 MB at +16 MB
    // CSR-build transients aliased into A (A first written by gemm1, after build)
    int* deg    = (int*)A;
    int* ex     = (int*)((char*)A + (size_t)N_NODES * 4);
    int* cursor = (int*)((char*)A + 2 * (size_t)N_NODES * 4);
    int* bsum   = (int*)((char*)A + 3 * (size_t)N_NODES * 4);

    const int BT = 256;
    const int NB_NODES = (N_NODES + 255) / 256;          // 782
    const int gemm_grid = N_NODES / 64;                  // 3125 (exact)
    const int gath_grid = 2048;

    // ---- CSR build + normalization + batch histogram ----
    hipMemsetAsync(deg, 0, (size_t)N_NODES * 4, stream);
    hipMemsetAsync(gsum, 0, (size_t)N_GRAPHS * 8, stream);   // gsum + cnts
    deg_kernel<<<(N_EDGES + BT - 1) / BT, BT, 0, stream>>>(dst, deg);
    batch_cnt_kernel<<<NB_NODES, BT, 0, stream>>>(batch, cnts);
    scan_block_kernel<<<NB_NODES, 256, 0, stream>>>(deg, ex, bsum, dis);
    scan_top_kernel<<<1, 1024, 0, stream>>>(bsum, NB_NODES);
    scan_add_kernel<<<NB_NODES, 256, 0, stream>>>(ex, bsum, row_start, cursor);
    place_kernel<<<(N_EDGES + BT - 1) / BT, BT, 0, stream>>>(src, dst, cursor, csr);

    // ---- layer 1 (aggregate-first on padded 11-wide, then fused GEMM+bias+relu) ----
    xscale_kernel<<<(N_NODES * XP + BT - 1) / BT, BT, 0, stream>>>(x, dis, xs);
    gather1_kernel<<<gath_grid, BT, 0, stream>>>(row_start, csr, xs, dis, P);
    gemm_tile_kernel<F_IN, false><<<gemm_grid, BT, 0, stream>>>(P, W1, dis, b1, A);

    // ---- layer 2: GEMM (f32->fp16, *dis) then fp16 gather -> f32 ----
    gemm_tile_kernel<H, true><<<gemm_grid, BT, 0, stream>>>(A, W2, dis, b2, Bsh);
    gather_kernel<<<gath_grid, BT, 0, stream>>>(row_start, csr, Bsh, dis, b2, A);

    // ---- layer 3: GEMM (f32->fp16, *dis) then fp16 gather + dot + scalar pool ----
    gemm_tile_kernel<H, true><<<gemm_grid, BT, 0, stream>>>(A, W3, dis, b3, Bsh);
    gather_dot_pool_kernel<<<gath_grid, BT, 0, stream>>>(row_start, csr, Bsh, dis, lw,
                                                         batch, gsum);

    // ---- head ----
    head2_kernel<<<(N_GRAPHS + BT - 1) / BT, BT, 0, stream>>>(gsum, cnts, b3, lw, lb, out);
}

// Round 9
// 421.313 us; speedup vs baseline: 1.1906x; 1.1906x over previous
//
#include <hip/hip_runtime.h>
#include <hip/hip_fp16.h>

#define N_NODES 200000
#define N_EDGES 1000000
#define N_GRAPHS 4096
#define F_IN 11
#define H 64
#define XP 16   // padded row stride for 11-wide buffers

// ---------------- degree histogram over dst ----------------

__global__ void deg_kernel(const int* __restrict__ dst, int* __restrict__ deg) {
    int i = blockIdx.x * blockDim.x + threadIdx.x;
    if (i < N_EDGES) atomicAdd(&deg[dst[i]], 1);
}

__global__ void batch_cnt_kernel(const int* __restrict__ batch, int* __restrict__ cnts) {
    int i = blockIdx.x * blockDim.x + threadIdx.x;
    if (i < N_NODES) atomicAdd(&cnts[batch[i]], 1);
}

// ---------------- CSR build: block scan + top scan + add + place ----------------

__global__ void scan_block_kernel(const int* __restrict__ deg, int* __restrict__ ex,
                                  int* __restrict__ bsum, float* __restrict__ dis) {
    __shared__ int sh[256];
    int i = blockIdx.x * 256 + threadIdx.x;
    int v = (i < N_NODES) ? deg[i] : 0;
    if (i < N_NODES) dis[i] = rsqrtf((float)(v + 1));   // +1 self loop
    sh[threadIdx.x] = v;
    __syncthreads();
    for (int o = 1; o < 256; o <<= 1) {
        int t = (threadIdx.x >= o) ? sh[threadIdx.x - o] : 0;
        __syncthreads();
        sh[threadIdx.x] += t;
        __syncthreads();
    }
    if (i < N_NODES) ex[i] = sh[threadIdx.x] - v;       // exclusive
    if (threadIdx.x == 255) bsum[blockIdx.x] = sh[255];
}

__global__ void scan_top_kernel(int* __restrict__ bsum, int nb) {
    __shared__ int sh[1024];
    int v = ((int)threadIdx.x < nb) ? bsum[threadIdx.x] : 0;
    sh[threadIdx.x] = v;
    __syncthreads();
    for (int o = 1; o < 1024; o <<= 1) {
        int t = ((int)threadIdx.x >= o) ? sh[threadIdx.x - o] : 0;
        __syncthreads();
        sh[threadIdx.x] += t;
        __syncthreads();
    }
    if ((int)threadIdx.x < nb) bsum[threadIdx.x] = sh[threadIdx.x] - v;
}

__global__ void scan_add_kernel(const int* __restrict__ ex, const int* __restrict__ boff,
                                int* __restrict__ row_start, int* __restrict__ cursor) {
    int i = blockIdx.x * 256 + threadIdx.x;
    if (i >= N_NODES) return;
    int r = ex[i] + boff[i >> 8];
    row_start[i] = r;
    cursor[i] = r;
    if (i == 0) row_start[N_NODES] = N_EDGES;
}

__global__ void place_kernel(const int* __restrict__ src, const int* __restrict__ dst,
                             int* __restrict__ cursor, int* __restrict__ csr) {
    int e = blockIdx.x * blockDim.x + threadIdx.x;
    if (e < N_EDGES) {
        int p = atomicAdd(&cursor[dst[e]], 1);
        csr[p] = src[e];
    }
}

// ---------------- w3l = W3 @ lw (64 floats) ----------------

__global__ void w3l_kernel(const float* __restrict__ W3, const float* __restrict__ lw,
                           float* __restrict__ w3l) {
    int k = threadIdx.x;
    if (k < H) {
        float s = 0.f;
#pragma unroll
        for (int j = 0; j < H; ++j) s += W3[k * H + j] * lw[j];
        w3l[k] = s;
    }
}

// ---------------- xs[row*16+c] = x*dis (c<11), 0 pad ----------------

__global__ void xscale_kernel(const float* __restrict__ x, const float* __restrict__ dis,
                              float* __restrict__ xs) {
    int i = blockIdx.x * blockDim.x + threadIdx.x;
    if (i < N_NODES * XP) {
        int row = i >> 4;
        int c = i & 15;
        xs[i] = (c < F_IN) ? x[(size_t)row * F_IN + c] * dis[row] : 0.f;
    }
}

// ---------------- layer-1 gather on padded 16-wide xs ----------------
// 4 nodes per wave: u = lane>>4, c = lane&15. P[n*16+c] = dis[n]*sum (pad cols sum zeros).

__global__ void gather1_kernel(const int* __restrict__ row_start, const int* __restrict__ csr,
                               const float* __restrict__ xs, const float* __restrict__ dis,
                               float* __restrict__ P) {
    int lane = threadIdx.x & 63;
    int c = lane & 15;
    int u = lane >> 4;
    int wave = (blockIdx.x * blockDim.x + threadIdx.x) >> 6;
    int nw = (gridDim.x * blockDim.x) >> 6;
    for (int n4 = wave * 4; n4 < N_NODES; n4 += nw * 4) {
        int n = n4 + u;
        int e0 = row_start[n], e1 = row_start[n + 1];
        float acc = xs[(size_t)n * XP + c];            // self loop
        int e = e0;
        for (; e + 4 <= e1; e += 4) {
            int s0 = csr[e], s1 = csr[e + 1], s2 = csr[e + 2], s3 = csr[e + 3];
            float v0 = xs[(size_t)s0 * XP + c];
            float v1 = xs[(size_t)s1 * XP + c];
            float v2 = xs[(size_t)s2 * XP + c];
            float v3 = xs[(size_t)s3 * XP + c];
            acc += (v0 + v1) + (v2 + v3);
        }
        for (; e < e1; ++e) acc += xs[(size_t)csr[e] * XP + c];
        P[(size_t)n * XP + c] = acc * dis[n];
    }
}

// ---------------- register-tiled dense transform ----------------
// 64 rows/block, 256 threads, 4x4 per thread.
// HALF_OUT: Y = half((X@W)*dis[row]).  else: Y = relu(X@W + bias) f32.

template <int K, bool HALF_OUT>
__global__ void gemm_tile_kernel(const float* __restrict__ X, const float* __restrict__ W,
                                 const float* __restrict__ dis, const float* __restrict__ bias,
                                 void* __restrict__ Y) {
    constexpr int KS = (K == F_IN) ? XP : K;
    __shared__ float Xt[KS][68];
    __shared__ float Ws[K][64];
    int tid = threadIdx.x;
    int rowbase = blockIdx.x * 64;

    for (int i = tid; i < K * 64; i += 256) Ws[i >> 6][i & 63] = W[i];

    if (K == 64) {
        for (int t = tid; t < 1024; t += 256) {
            int r = t >> 4;
            int kc = (t & 15) * 4;
            float4 v = *(const float4*)(X + (size_t)(rowbase + r) * 64 + kc);
            Xt[kc + 0][r] = v.x;
            Xt[kc + 1][r] = v.y;
            Xt[kc + 2][r] = v.z;
            Xt[kc + 3][r] = v.w;
        }
    } else {
        // padded rows of 16 floats: 64*16 = 1024 floats = 256 float4, 1/thread
        int r = tid >> 2;
        int c4 = (tid & 3) * 4;
        float4 v = *(const float4*)(X + (size_t)(rowbase + r) * XP + c4);
        Xt[c4 + 0][r] = v.x;
        Xt[c4 + 1][r] = v.y;
        Xt[c4 + 2][r] = v.z;
        Xt[c4 + 3][r] = v.w;
    }
    __syncthreads();

    int tc = (tid & 15) * 4;
    int tr = (tid >> 4) * 4;
    float a00 = 0, a01 = 0, a02 = 0, a03 = 0;
    float a10 = 0, a11 = 0, a12 = 0, a13 = 0;
    float a20 = 0, a21 = 0, a22 = 0, a23 = 0;
    float a30 = 0, a31 = 0, a32 = 0, a33 = 0;
#pragma unroll
    for (int k = 0; k < K; ++k) {
        float4 xv = *(const float4*)&Xt[k][tr];
        float4 wv = *(const float4*)&Ws[k][tc];
        a00 += xv.x * wv.x; a01 += xv.x * wv.y; a02 += xv.x * wv.z; a03 += xv.x * wv.w;
        a10 += xv.y * wv.x; a11 += xv.y * wv.y; a12 += xv.y * wv.z; a13 += xv.y * wv.w;
        a20 += xv.z * wv.x; a21 += xv.z * wv.y; a22 += xv.z * wv.z; a23 += xv.z * wv.w;
        a30 += xv.w * wv.x; a31 += xv.w * wv.y; a32 += xv.w * wv.z; a33 += xv.w * wv.w;
    }
    float acc[4][4] = {{a00, a01, a02, a03}, {a10, a11, a12, a13},
                       {a20, a21, a22, a23}, {a30, a31, a32, a33}};
    float4 bv = {0, 0, 0, 0};
    if (!HALF_OUT) bv = *(const float4*)(bias + tc);
#pragma unroll
    for (int i = 0; i < 4; ++i) {
        int row = rowbase + tr + i;
        if (HALF_OUT) {
            float d = dis[row];
            union { uint2 u; __half2 h[2]; } pk;
            pk.h[0] = __floats2half2_rn(acc[i][0] * d, acc[i][1] * d);
            pk.h[1] = __floats2half2_rn(acc[i][2] * d, acc[i][3] * d);
            *(uint2*)((__half*)Y + (size_t)row * 64 + tc) = pk.u;
        } else {
            float4 o;
            o.x = fmaxf(acc[i][0] + bv.x, 0.f);
            o.y = fmaxf(acc[i][1] + bv.y, 0.f);
            o.z = fmaxf(acc[i][2] + bv.z, 0.f);
            o.w = fmaxf(acc[i][3] + bv.w, 0.f);
            *(float4*)((float*)Y + (size_t)row * 64 + tc) = o;
        }
    }
}

// ---------------- layer-2 gather (fp16) with fused h2->y epilogue ----------------
// lane = g*16 + q. h2[n] = relu(dis[n]*sum_slots Bsh[src] + b2) lives in registers;
// y[n] = dis[n] * dot(h2[n], w3l) written as one scalar per node.

__global__ void gather_fused_kernel(const int* __restrict__ row_start,
                                    const int* __restrict__ csr,
                                    const __half* __restrict__ Bsh,
                                    const float* __restrict__ dis,
                                    const float* __restrict__ b2,
                                    const float* __restrict__ w3l,
                                    float* __restrict__ y) {
    int lane = threadIdx.x & 63;
    int q = lane & 15;
    int g = lane >> 4;
    int wave = (blockIdx.x * blockDim.x + threadIdx.x) >> 6;
    int nw = (gridDim.x * blockDim.x) >> 6;
    float4 bi = ((const float4*)b2)[q];
    float4 wl = ((const float4*)w3l)[q];
    for (int n = wave; n < N_NODES; n += nw) {
        int e0 = row_start[n], e1 = row_start[n + 1];
        int nslots = e1 - e0 + 1;
        float4 acc = {0.f, 0.f, 0.f, 0.f};
        for (int base = 0; base < nslots; base += 4) {
            int slot = base + g;
            if (slot < nslots) {
                int s = (slot == 0) ? n : csr[e0 + slot - 1];
                union { uint2 u; __half2 h[2]; } r;
                r.u = *(const uint2*)(Bsh + (size_t)s * 64 + q * 4);
                float2 f0 = __half22float2(r.h[0]);
                float2 f1 = __half22float2(r.h[1]);
                acc.x += f0.x; acc.y += f0.y; acc.z += f1.x; acc.w += f1.y;
            }
        }
#pragma unroll
        for (int m = 16; m <= 32; m <<= 1) {
            acc.x += __shfl_xor(acc.x, m, 64);
            acc.y += __shfl_xor(acc.y, m, 64);
            acc.z += __shfl_xor(acc.z, m, 64);
            acc.w += __shfl_xor(acc.w, m, 64);
        }
        if (g == 0) {          // lanes 0..15 all active here
            float d = dis[n];
            float ox = fmaxf(acc.x * d + bi.x, 0.f);
            float oy = fmaxf(acc.y * d + bi.y, 0.f);
            float oz = fmaxf(acc.z * d + bi.z, 0.f);
            float ow = fmaxf(acc.w * d + bi.w, 0.f);
            float p = ox * wl.x + oy * wl.y + oz * wl.z + ow * wl.w;
#pragma unroll
            for (int m = 1; m <= 8; m <<= 1) p += __shfl_xor(p, m, 64);
            if (q == 0) y[n] = p * d;
        }
    }
}

// ---------------- scalar pool: gsum[batch[n]] += dis[n]*(sum_src y + y[n]) ----------

__global__ void pool_scalar_kernel(const int* __restrict__ row_start,
                                   const int* __restrict__ csr,
                                   const float* __restrict__ y,
                                   const float* __restrict__ dis,
                                   const int* __restrict__ batch,
                                   float* __restrict__ gsum) {
    int n = blockIdx.x * blockDim.x + threadIdx.x;
    if (n >= N_NODES) return;
    int e0 = row_start[n], e1 = row_start[n + 1];
    float s = y[n];
    int e = e0;
    for (; e + 4 <= e1; e += 4) {
        float v0 = y[csr[e]], v1 = y[csr[e + 1]], v2 = y[csr[e + 2]], v3 = y[csr[e + 3]];
        s += (v0 + v1) + (v2 + v3);
    }
    for (; e < e1; ++e) s += y[csr[e]];
    atomicAdd(&gsum[batch[n]], s * dis[n]);
}

// ---------------- head: out[g] = gsum/cnt + dot(b3,lw) + lb ----------------

__global__ void head2_kernel(const float* __restrict__ gsum, const int* __restrict__ cnts,
                             const float* __restrict__ b3, const float* __restrict__ lw,
                             const float* __restrict__ lb, float* __restrict__ out) {
    int g = blockIdx.x * blockDim.x + threadIdx.x;
    if (g >= N_GRAPHS) return;
    float cb = 0.f;
#pragma unroll
    for (int k = 0; k < H; ++k) cb += b3[k] * lw[k];
    int c = cnts[g];
    out[g] = (c > 0) ? (gsum[g] / (float)c + cb + lb[0]) : lb[0];
}

extern "C" void kernel_launch(void* const* d_in, const int* in_sizes, int n_in,
                              void* d_out, int out_size, void* d_ws, size_t ws_size,
                              hipStream_t stream) {
    const float* x     = (const float*)d_in[0];
    const int*   ei    = (const int*)d_in[1];
    const int*   batch = (const int*)d_in[2];
    const float* W1    = (const float*)d_in[3];
    const float* b1    = (const float*)d_in[4];
    const float* W2    = (const float*)d_in[5];
    const float* b2    = (const float*)d_in[6];
    const float* W3    = (const float*)d_in[7];
    const float* b3    = (const float*)d_in[8];
    const float* lw    = (const float*)d_in[9];
    const float* lb    = (const float*)d_in[10];
    float* out = (float*)d_out;

    const int* src = ei;
    const int* dst = ei + N_EDGES;

    const size_t NH = (size_t)N_NODES * H;
    char* ws = (char*)d_ws;
    float*  A         = (float*)ws;                                    // 51.2 MB (h1 f32)
    char*   Bregion   = ws + NH * 4;                                   // 51.2 MB
    __half* Bsh       = (__half*)Bregion;                              // 25.6 MB fp16 staging
    float*  dis       = (float*)(ws + 2 * NH * 4);                     // 0.8 MB
    int*    row_start = (int*)(ws + 2 * NH * 4 + (size_t)N_NODES * 4); // 0.8 MB (+1)
    int*    csr       = (int*)((char*)row_start + ((size_t)N_NODES + 1) * 4); // 4 MB
    float*  gsum      = (float*)((char*)csr + (size_t)N_EDGES * 4);    // 16 KB
    int*    cnts      = (int*)((char*)gsum + (size_t)N_GRAPHS * 4);    // 16 KB
    float*  w3l       = (float*)((char*)cnts + (size_t)N_GRAPHS * 4);  // 256 B
    // y aliases A's head: h1 (A) is last read by gemm2, which completes before
    // gather_fused writes y.
    float*  y = A;                                                     // 0.8 MB
    // layer-1 transients inside B region (consumed before Bsh is written by gemm2)
    float* xs = (float*)Bregion;                        // 12.8 MB (16-padded)
    float* P  = (float*)(Bregion + (16u << 20));        // 12.8 MB at +16 MB
    // CSR-build transients aliased into A (A first written by gemm1, after build)
    int* deg    = (int*)A;
    int* ex     = (int*)((char*)A + (size_t)N_NODES * 4);
    int* cursor = (int*)((char*)A + 2 * (size_t)N_NODES * 4);
    int* bsum   = (int*)((char*)A + 3 * (size_t)N_NODES * 4);

    const int BT = 256;
    const int NB_NODES = (N_NODES + 255) / 256;          // 782
    const int gemm_grid = N_NODES / 64;                  // 3125 (exact)
    const int gath_grid = 2048;

    // ---- CSR build + normalization + batch histogram ----
    hipMemsetAsync(deg, 0, (size_t)N_NODES * 4, stream);
    hipMemsetAsync(gsum, 0, (size_t)N_GRAPHS * 8, stream);   // gsum + cnts
    deg_kernel<<<(N_EDGES + BT - 1) / BT, BT, 0, stream>>>(dst, deg);
    batch_cnt_kernel<<<NB_NODES, BT, 0, stream>>>(batch, cnts);
    scan_block_kernel<<<NB_NODES, 256, 0, stream>>>(deg, ex, bsum, dis);
    scan_top_kernel<<<1, 1024, 0, stream>>>(bsum, NB_NODES);
    scan_add_kernel<<<NB_NODES, 256, 0, stream>>>(ex, bsum, row_start, cursor);
    place_kernel<<<(N_EDGES + BT - 1) / BT, BT, 0, stream>>>(src, dst, cursor, csr);
    w3l_kernel<<<1, 64, 0, stream>>>(W3, lw, w3l);

    // ---- layer 1 (aggregate-first on padded 11-wide, then fused GEMM+bias+relu) ----
    xscale_kernel<<<(N_NODES * XP + BT - 1) / BT, BT, 0, stream>>>(x, dis, xs);
    gather1_kernel<<<gath_grid, BT, 0, stream>>>(row_start, csr, xs, dis, P);
    gemm_tile_kernel<F_IN, false><<<gemm_grid, BT, 0, stream>>>(P, W1, dis, b1, A);

    // ---- layer 2: GEMM (f32->fp16, *dis) then fused gather -> y scalars ----
    gemm_tile_kernel<H, true><<<gemm_grid, BT, 0, stream>>>(A, W2, dis, b2, Bsh);
    gather_fused_kernel<<<gath_grid, BT, 0, stream>>>(row_start, csr, Bsh, dis, b2, w3l, y);

    // ---- layer 3 as scalar gather-pool over y (L2-resident) ----
    pool_scalar_kernel<<<NB_NODES, BT, 0, stream>>>(row_start, csr, y, dis, batch, gsum);

    // ---- head ----
    head2_kernel<<<(N_GRAPHS + BT - 1) / BT, BT, 0, stream>>>(gsum, cnts, b3, lw, lb, out);
}